// Round 5
// baseline (511.788 us; speedup 1.0000x reference)
//
#include <hip/hip_runtime.h>

#define XDIM 256
#define YDIM 256
#define ZDIM 32
#define NT 384
#define NA 180
#define AG 6                 // angles per block -> grid (32, 30)
#define SC 261               // cell stride per row (260 used + 1 pad); 261%16=5, gcd(5,16)=1
#define CROWS 68             // cell rows per phase: y0 in [64p-2 .. 64p+65]
#define NCX 260              // cells per row: x0 in [-2 .. 257]
#define SMEM_BYTES (CROWS * SC * 8)  // 141984 < 160K

typedef _Float16 h2 __attribute__((ext_vector_type(2)));

// Quad-packed bilinear cells: cell(y0,x0) = 8B = fp16 x4 =
// {vol[y0][x0], vol[y0][x0+1], vol[y0+1][x0], vol[y0+1][x0+1]} (zero outside
// the volume -> reference's valid_clip weight-zeroing falls out for free).
// One ds_read_b64 per bilinear sample. 4 y-phases of 64 rows; rays
// t-partitioned at exact crossings (identical FP expression in every phase
// => consistent partition; guard rows absorb float slack).
// t-interval is trimmed with floor/ceil (NOT widened then truncated): first
// sample overshoots each crossing by at most 1 step -> x,y >= -2 stays inside
// the staged x0,y0 >= -2 pad cells. (R4's -1 widening + trunc gave 2-step
// overshoot -> x0f=-3 -> read of the never-written row pad -> stale-LDS NaN.)
__global__ __launch_bounds__(1024) void proj_kernel(
    const float* __restrict__ vol,
    const float* __restrict__ phis,
    float* __restrict__ out) {
  extern __shared__ char smem[];
  uint2* cells = reinterpret_cast<uint2*>(smem);

  const int tid = threadIdx.x;
  const int z = blockIdx.x;   // 0..31
  const int ag = blockIdx.y;  // 0..29

  const int col = tid >> 2;   // 0..255
  const int q = tid & 3;      // t-quarter
  const float u = (float)col - 127.5f;

  float acc[AG];
#pragma unroll
  for (int j = 0; j < AG; ++j) acc[j] = 0.f;

  const float* src = vol + z * (YDIM * XDIM);

  for (int ph = 0; ph < 4; ++ph) {
    const int R0 = 64 * ph - 2;  // first cell row (volume y0)
    __syncthreads();  // previous phase's readers done before overwrite

    // ---- stage cells (bounds-checked; OOB reads as 0) ----
    for (int k = tid; k < CROWS * NCX; k += 1024) {
      int Lyo = k / NCX;
      int Lx = k - Lyo * NCX;
      int y0 = R0 + Lyo;
      int x0 = Lx - 2;
      bool ya = (unsigned)y0 < 256u, yb = (unsigned)(y0 + 1) < 256u;
      bool xa = (unsigned)x0 < 256u, xb = (unsigned)(x0 + 1) < 256u;
      const float* rp = src + y0 * XDIM + x0;
      float v00 = (ya && xa) ? rp[0] : 0.f;
      float v01 = (ya && xb) ? rp[1] : 0.f;
      float v10 = (yb && xa) ? rp[XDIM] : 0.f;
      float v11 = (yb && xb) ? rp[XDIM + 1] : 0.f;
      h2 cl = __builtin_bit_cast(h2, __builtin_amdgcn_cvt_pkrtz(v00, v01));
      h2 ch = __builtin_bit_cast(h2, __builtin_amdgcn_cvt_pkrtz(v10, v11));
      cells[Lyo * SC + Lx] =
          make_uint2(__builtin_bit_cast(unsigned, cl), __builtin_bit_cast(unsigned, ch));
    }
    // zero the per-row pad cell (Lx=260): insurance so a +-1 cell slip reads
    // 0.0, never stale LDS
    for (int r = tid; r < CROWS; r += 1024)
      cells[r * SC + (SC - 1)] = make_uint2(0u, 0u);
    __syncthreads();

    const int KP = 2 - R0 * SC;  // cell index = y0f*SC + x0f + KP

    for (int j = 0; j < AG; ++j) {
      const int a = ag * AG + j;
      const float phi = phis[a] * 0.017453292519943295f;
      const float c = cosf(phi);
      const float s = sinf(phi);
      const float bx = fmaf(u, -s, 127.5f);  // x(it) = bx + (it-191.5)*c
      const float by = fmaf(u, c, 127.5f);   // y(it) = by + (it-191.5)*s

      // box trim to x,y in (-1,256); floor/ceil keeps every in-range sample
      // and overshoots each crossing by at most one step
      float lo = 0.f, hi = (float)NT;
      if (fabsf(c) < 1e-6f) {
        if (bx <= -1.f || bx >= 256.f) { lo = 1.f; hi = 0.f; }
      } else {
        float invc = 1.f / c;
        float t1 = fmaf(-1.f - bx, invc, 191.5f);
        float t2 = fmaf(256.f - bx, invc, 191.5f);
        lo = fmaxf(lo, fminf(t1, t2));
        hi = fminf(hi, fmaxf(t1, t2));
      }
      int itP0, itP1;
      if (fabsf(s) < 1e-5f) {
        if (by <= -1.f || by >= 256.f) { lo = 1.f; hi = 0.f; }
        int pstar = min(3, max(0, ((int)floorf(by)) >> 6));
        itP0 = (ph == pstar) ? 0 : 1;
        itP1 = (ph == pstar) ? NT : 0;
      } else {
        float invs = 1.f / s;
        float t1 = fmaf(-1.f - by, invs, 191.5f);
        float t2 = fmaf(256.f - by, invs, 191.5f);
        lo = fmaxf(lo, fminf(t1, t2));
        hi = fminf(hi, fmaxf(t1, t2));
        // phase partition at y = {63,127,191}; identical expression in every
        // phase => exact, gap/overlap-free assignment
        const float BL = 64.f * ph - 1.f;   // lower boundary value for band
        const float BH = 64.f * ph + 63.f;  // upper
        if (s > 0.f) {
          itP0 = (ph == 0) ? -2000000000 : (int)ceilf(fmaf(BL, invs, fmaf(-by, invs, 191.5f)));
          itP1 = (ph == 3) ? 2000000000 : (int)ceilf(fmaf(BH, invs, fmaf(-by, invs, 191.5f)));
        } else {
          itP0 = (ph == 3) ? -2000000000 : (int)floorf(fmaf(BH, invs, fmaf(-by, invs, 191.5f))) + 1;
          itP1 = (ph == 0) ? 2000000000 : (int)floorf(fmaf(BL, invs, fmaf(-by, invs, 191.5f))) + 1;
        }
      }
      int itA = (int)floorf(lo);                      // lo >= 0
      int itB = (int)ceilf(fminf(hi, (float)NT));     // <= NT
      int s0 = max(itA, itP0);
      int s1 = min(itB, itP1);

      int start = s0 + ((q - s0) & 3);
      float t0 = (float)start - 191.5f;
      float x = fmaf(t0, c, bx);
      float y = fmaf(t0, s, by);
      const float dx = 4.f * c, dy = 4.f * s;
      float a_ = acc[j];
      for (int it = start; it < s1; it += 4) {
        float x0f = floorf(x);
        float y0f = floorf(y);
        float fx = x - x0f;
        float fy = y - y0f;
        int ii = (int)fmaf(y0f, (float)SC, x0f) + KP;  // exact: |vals| < 2^24
        uint2 cell = cells[ii];                         // ds_read_b64
        h2 cl = __builtin_bit_cast(h2, cell.x);
        h2 ch = __builtin_bit_cast(h2, cell.y);
        h2 wx = __builtin_bit_cast(h2, __builtin_amdgcn_cvt_pkrtz(1.f - fx, fx));
#if __has_builtin(__builtin_amdgcn_fdot2)
        float h0 = __builtin_amdgcn_fdot2(cl, wx, 0.f, false);
        float h1 = __builtin_amdgcn_fdot2(ch, wx, 0.f, false);
#else
        float h0 = (float)cl[0] * (float)wx[0] + (float)cl[1] * (float)wx[1];
        float h1 = (float)ch[0] * (float)wx[0] + (float)ch[1] * (float)wx[1];
#endif
        a_ = fmaf(h0, 1.f - fy, a_);
        a_ = fmaf(h1, fy, a_);
        x += dx;
        y += dy;
      }
      acc[j] = a_;
    }
  }

  // reduce 4 t-quarters (adjacent lanes) and store
#pragma unroll
  for (int j = 0; j < AG; ++j) {
    float v = acc[j];
    v += __shfl_xor(v, 1, 64);
    v += __shfl_xor(v, 2, 64);
    if (q == 0) {
      int a = ag * AG + j;
      out[(a * ZDIM + z) * XDIM + col] = v;
    }
  }
}

extern "C" void kernel_launch(void* const* d_in, const int* in_sizes, int n_in,
                              void* d_out, int out_size, void* d_ws, size_t ws_size,
                              hipStream_t stream) {
  const float* vol = (const float*)d_in[0];
  const float* phis = (const float*)d_in[1];
  float* out = (float*)d_out;
  (void)hipFuncSetAttribute((const void*)proj_kernel,
                            hipFuncAttributeMaxDynamicSharedMemorySize,
                            SMEM_BYTES);
  dim3 grid(ZDIM, NA / AG);
  proj_kernel<<<grid, 1024, SMEM_BYTES, stream>>>(vol, phis, out);
}

// Round 6
// 414.339 us; speedup vs baseline: 1.2352x; 1.2352x over previous
//
#include <hip/hip_runtime.h>

#define XDIM 256
#define YDIM 256
#define ZDIM 32
#define NT 384
#define NA 180
#define NASPL 4              // angle splits -> 45 angles per block
#define NANG (NA / NASPL)
#define SC 261               // cell stride per row; odd, spreads banks
#define CROWS 68             // cell rows per band: y0 in [64b-2 .. 64b+65]
#define NCX 260              // cells per row: x0 in [-2 .. 257]
#define SMEM_BYTES (CROWS * SC * 8)  // 141984 < 160K

typedef _Float16 h2 __attribute__((ext_vector_type(2)));

// Block = (z, 64-row band, angle-quarter). Quad-packed fp16 bilinear cells
// (one ds_read_b64 per sample) staged ONCE per block; then 45 angles marched
// with no barriers. Per-band sample count is angle-uniform (~64*256), so
// blocks are load-balanced by construction — this removes R5's 1.54x
// phase-imbalance (1 block/CU + consecutive-angle groups + phase barriers).
// Cross-band accumulation via HW f32 global atomics onto a zeroed output.
// Numerics identical to R5 (passed): exact band partition via identical FP
// expressions in adjacent blocks; floor/ceil trim overshoots <=1 step, which
// the +-2 guard rows / pad cells absorb.
__global__ __launch_bounds__(1024) void proj_kernel(
    const float* __restrict__ vol,
    const float* __restrict__ phis,
    float* __restrict__ out) {
  extern __shared__ char smem[];
  uint2* cells = reinterpret_cast<uint2*>(smem);

  const int tid = threadIdx.x;
  const int z = blockIdx.x;    // 0..31
  const int b = blockIdx.y;    // band 0..3
  const int as = blockIdx.z;   // angle split 0..3

  const int col = tid >> 2;    // 0..255
  const int q = tid & 3;       // t-quarter
  const float u = (float)col - 127.5f;

  const float* src = vol + z * (YDIM * XDIM);
  const int R0 = 64 * b - 2;   // first cell row (volume y0)

  // ---- stage band cells (bounds-checked; OOB reads as 0) ----
  for (int k = tid; k < CROWS * NCX; k += 1024) {
    int Lyo = k / NCX;
    int Lx = k - Lyo * NCX;
    int y0 = R0 + Lyo;
    int x0 = Lx - 2;
    bool ya = (unsigned)y0 < 256u, yb = (unsigned)(y0 + 1) < 256u;
    bool xa = (unsigned)x0 < 256u, xb = (unsigned)(x0 + 1) < 256u;
    const float* rp = src + y0 * XDIM + x0;
    float v00 = (ya && xa) ? rp[0] : 0.f;
    float v01 = (ya && xb) ? rp[1] : 0.f;
    float v10 = (yb && xa) ? rp[XDIM] : 0.f;
    float v11 = (yb && xb) ? rp[XDIM + 1] : 0.f;
    h2 cl = __builtin_bit_cast(h2, __builtin_amdgcn_cvt_pkrtz(v00, v01));
    h2 ch = __builtin_bit_cast(h2, __builtin_amdgcn_cvt_pkrtz(v10, v11));
    cells[Lyo * SC + Lx] =
        make_uint2(__builtin_bit_cast(unsigned, cl), __builtin_bit_cast(unsigned, ch));
  }
  // zero per-row pad cell (Lx=260): a +-1 cell slip reads 0.0, never stale LDS
  for (int r = tid; r < CROWS; r += 1024)
    cells[r * SC + (SC - 1)] = make_uint2(0u, 0u);
  __syncthreads();

  const int KP = 2 - R0 * SC;  // cell index = y0f*SC + x0f + KP
  const float BL = 64.f * b - 1.f;   // band lower y boundary
  const float BH = 64.f * b + 63.f;  // band upper y boundary

  for (int j = 0; j < NANG; ++j) {
    const int a = as * NANG + j;
    const float phi = phis[a] * 0.017453292519943295f;
    const float c = cosf(phi);
    const float s = sinf(phi);
    const float bx = fmaf(u, -s, 127.5f);  // x(it) = bx + (it-191.5)*c
    const float by = fmaf(u, c, 127.5f);   // y(it) = by + (it-191.5)*s

    // box trim to x,y in (-1,256); floor/ceil keeps every in-range sample,
    // overshoots each crossing by at most one step (guards absorb it)
    float lo = 0.f, hi = (float)NT;
    if (fabsf(c) < 1e-6f) {
      if (bx <= -1.f || bx >= 256.f) { lo = 1.f; hi = 0.f; }
    } else {
      float invc = 1.f / c;
      float t1 = fmaf(-1.f - bx, invc, 191.5f);
      float t2 = fmaf(256.f - bx, invc, 191.5f);
      lo = fmaxf(lo, fminf(t1, t2));
      hi = fminf(hi, fmaxf(t1, t2));
    }
    int itP0, itP1;
    if (fabsf(s) < 1e-5f) {
      if (by <= -1.f || by >= 256.f) { lo = 1.f; hi = 0.f; }
      int pstar = min(3, max(0, ((int)floorf(by)) >> 6));
      itP0 = (b == pstar) ? 0 : 1;
      itP1 = (b == pstar) ? NT : 0;
    } else {
      float invs = 1.f / s;
      float t1 = fmaf(-1.f - by, invs, 191.5f);
      float t2 = fmaf(256.f - by, invs, 191.5f);
      lo = fmaxf(lo, fminf(t1, t2));
      hi = fminf(hi, fmaxf(t1, t2));
      // band partition at y = {63,127,191}; identical expressions in adjacent
      // blocks => exact, gap/overlap-free assignment
      if (s > 0.f) {
        itP0 = (b == 0) ? -2000000000 : (int)ceilf(fmaf(BL, invs, fmaf(-by, invs, 191.5f)));
        itP1 = (b == 3) ? 2000000000 : (int)ceilf(fmaf(BH, invs, fmaf(-by, invs, 191.5f)));
      } else {
        itP0 = (b == 3) ? -2000000000 : (int)floorf(fmaf(BH, invs, fmaf(-by, invs, 191.5f))) + 1;
        itP1 = (b == 0) ? 2000000000 : (int)floorf(fmaf(BL, invs, fmaf(-by, invs, 191.5f))) + 1;
      }
    }
    int itA = (int)floorf(lo);                   // lo >= 0
    int itB = (int)ceilf(fminf(hi, (float)NT));  // <= NT
    int s0 = max(itA, itP0);
    int s1 = min(itB, itP1);

    int start = s0 + ((q - s0) & 3);
    float t0 = (float)start - 191.5f;
    float x = fmaf(t0, c, bx);
    float y = fmaf(t0, s, by);
    const float dx = 4.f * c, dy = 4.f * s;
    float a_ = 0.f;
    for (int it = start; it < s1; it += 4) {
      float x0f = floorf(x);
      float y0f = floorf(y);
      float fx = x - x0f;
      float fy = y - y0f;
      int ii = (int)fmaf(y0f, (float)SC, x0f) + KP;  // exact: |vals| < 2^24
      uint2 cell = cells[ii];                         // ds_read_b64
      h2 cl = __builtin_bit_cast(h2, cell.x);
      h2 ch = __builtin_bit_cast(h2, cell.y);
      h2 wx = __builtin_bit_cast(h2, __builtin_amdgcn_cvt_pkrtz(1.f - fx, fx));
#if __has_builtin(__builtin_amdgcn_fdot2)
      float h0 = __builtin_amdgcn_fdot2(cl, wx, 0.f, false);
      float h1 = __builtin_amdgcn_fdot2(ch, wx, 0.f, false);
#else
      float h0 = (float)cl[0] * (float)wx[0] + (float)cl[1] * (float)wx[1];
      float h1 = (float)ch[0] * (float)wx[0] + (float)ch[1] * (float)wx[1];
#endif
      a_ = fmaf(h0, 1.f - fy, a_);
      a_ = fmaf(h1, fy, a_);
      x += dx;
      y += dy;
    }

    // reduce 4 t-quarters (adjacent lanes) and accumulate across bands
    a_ += __shfl_xor(a_, 1, 64);
    a_ += __shfl_xor(a_, 2, 64);
    if (q == 0 && a_ != 0.f)
      unsafeAtomicAdd(&out[(a * ZDIM + z) * XDIM + col], a_);
  }
}

extern "C" void kernel_launch(void* const* d_in, const int* in_sizes, int n_in,
                              void* d_out, int out_size, void* d_ws, size_t ws_size,
                              hipStream_t stream) {
  const float* vol = (const float*)d_in[0];
  const float* phis = (const float*)d_in[1];
  float* out = (float*)d_out;
  (void)hipFuncSetAttribute((const void*)proj_kernel,
                            hipFuncAttributeMaxDynamicSharedMemorySize,
                            SMEM_BYTES);
  hipMemsetAsync(out, 0, (size_t)out_size * sizeof(float), stream);
  dim3 grid(ZDIM, 4, NASPL);
  proj_kernel<<<grid, 1024, SMEM_BYTES, stream>>>(vol, phis, out);
}